// Round 12
// baseline (697.308 us; speedup 1.0000x reference)
//
#include <hip/hip_runtime.h>
#include <hip/hip_bf16.h>

#define B 64
#define N0 2048
#define DEG 16
#define IN_DIM 128
#define H 30
#define NH 11
#define K1 1844
#define K2 1660
#define K3 1494
#define NTOT (B * N0)        /* 131072 */
#define ETOT (NTOT * DEG)    /* 2097152 */
#define RSTRIDE 32           /* row stride for h */
#define ESTRIDE1 32768       /* layer-1 CSR capacity per graph */
#define RSEG 16              /* readout segments per graph */
/* rt layout: 4 planes [NTOT][16]; plane cg holds combined cols cg*15..cg*15+14
   (cg 0,1 = r cols 0-29; cg 2,3 = t cols 0-29). 16th col = pad -> every
   thread-store is one full aligned 64B line. */

// ---------------------------------------------------------------------------
// Prep: fold layernorm gamma into layer-1 weights; combine rel/root weights.
// ---------------------------------------------------------------------------
__global__ __launch_bounds__(256) void k_prep(
    const float* __restrict__ ln_g, const float* __restrict__ ln_b,
    const float* __restrict__ Wrel1, const float* __restrict__ brel1, const float* __restrict__ Wroot1,
    const float* __restrict__ Wrel2, const float* __restrict__ Wroot2,
    const float* __restrict__ Wrel3, const float* __restrict__ Wroot3,
    float* __restrict__ Wc1, float* __restrict__ S1, float* __restrict__ T1,
    float* __restrict__ Wc2, float* __restrict__ Wc3)
{
    int tid = threadIdx.x;
    for (int i = tid; i < IN_DIM * 60; i += 256) {
        int j = i / 60, c = i - j * 60;
        float w = (c < H) ? Wrel1[j * H + c] : Wroot1[j * H + (c - H)];
        Wc1[i] = w * ln_g[j];
    }
    if (tid < 60) {
        int c = tid;
        float s = 0.f, tt = 0.f;
        for (int j = 0; j < IN_DIM; ++j) {
            float w = (c < H) ? Wrel1[j * H + c] : Wroot1[j * H + (c - H)];
            s += w * ln_g[j];
            tt += w * ln_b[j];
        }
        S1[c] = s;
        T1[c] = (c < H) ? tt : tt + brel1[c - H];
    }
    for (int i = tid; i < H * 60; i += 256) {
        int j = i / 60, c = i - j * 60;
        Wc2[i] = (c < H) ? Wrel2[j * H + c] : Wroot2[j * H + (c - H)];
        Wc3[i] = (c < H) ? Wrel3[j * H + c] : Wroot3[j * H + (c - H)];
    }
}

// ---------------------------------------------------------------------------
// Layer 1 LN+proj v9: block = 64-row tile, x staged in LDS (coalesced).
// Wave w = col-group w (15 cols), lane = row. Thread dots its own LDS row;
// LN sums accumulated in-lane during the dot (no shuffles). Store = one full
// 64B line per thread, lane-consecutive rows -> coalesced 4KB per wave.
// Fixes round-11's transaction-issue bound (2048 -> 512 coalesced per block).
// ---------------------------------------------------------------------------
__global__ __launch_bounds__(256) void k_lnproj(
    const float* __restrict__ x, const float* __restrict__ Wc,
    const float* __restrict__ S, const float* __restrict__ T,
    float* __restrict__ rt)
{
    __shared__ float xt[64 * 132];             // 64 rows, stride 132 (pad)
    int row0 = blockIdx.x * 64;
    const float4* xg = (const float4*)(x + (size_t)row0 * IN_DIM);
#pragma unroll
    for (int q = 0; q < 8; ++q) {
        int i = q * 256 + threadIdx.x;         // 0..2047 float4 of the tile
        float4 v = xg[i];
        int r = i >> 5, c4 = i & 31;
        *(float4*)&xt[r * 132 + c4 * 4] = v;
    }
    __syncthreads();
    int lane = threadIdx.x & 63, cg = threadIdx.x >> 6;
    int row = row0 + lane;
    const float* wbase = Wc + cg * 15;
    const float* xr = &xt[lane * 132];
    float acc[15];
#pragma unroll
    for (int c = 0; c < 15; ++c) acc[c] = 0.f;
    float sum = 0.f, sumsq = 0.f;
    for (int k4 = 0; k4 < 32; ++k4) {
        float4 xq = *(const float4*)(xr + k4 * 4);
        float xs[4] = {xq.x, xq.y, xq.z, xq.w};
#pragma unroll
        for (int u = 0; u < 4; ++u) {
            float xv = xs[u];
            sum += xv; sumsq += xv * xv;
            const float* wrow = wbase + (k4 * 4 + u) * 60;   // wave-uniform
#pragma unroll
            for (int c = 0; c < 15; ++c) acc[c] += xv * wrow[c];
        }
    }
    float mean = sum * (1.f / 128.f);
    float var = sumsq * (1.f / 128.f) - mean * mean;
    float rstd = 1.0f / sqrtf(var + 1e-5f);
    int scol = cg * 15;
    float o[16];
#pragma unroll
    for (int c = 0; c < 15; ++c)
        o[c] = rstd * (acc[c] - mean * S[scol + c]) + T[scol + c];
    o[15] = 0.f;
    float4* op = (float4*)(rt + ((size_t)cg * NTOT + row) * 16);
    op[0] = make_float4(o[0], o[1], o[2], o[3]);
    op[1] = make_float4(o[4], o[5], o[6], o[7]);
    op[2] = make_float4(o[8], o[9], o[10], o[11]);
    op[3] = make_float4(o[12], o[13], o[14], o[15]);
}

// ---------------------------------------------------------------------------
// Pooled projection v5 (layers 2/3): block = 64 pooled rows; the 64 gathered
// h-rows staged ONCE in LDS (512 float4 vs round-11's 7168 per-thread
// gathers); vals[] shared. Wave w = col-group, lane = row.
// ---------------------------------------------------------------------------
__global__ __launch_bounds__(256) void k_proj30p(
    const float* __restrict__ hbuf, const int* __restrict__ sidx,
    const float* __restrict__ score, const float* __restrict__ Wc,
    const float* __restrict__ brel, float* __restrict__ rt,
    int n_old, int k)
{
    __shared__ float ht[64 * 36];              // 64 rows x 32 (+4 pad)
    __shared__ float vals[64];
    int row0 = blockIdx.x * 64;
#pragma unroll
    for (int q = 0; q < 2; ++q) {
        int i = q * 256 + threadIdx.x;         // 0..511: (row, c4)
        int rr = i >> 3, c4 = i & 7;
        int row = row0 + rr;
        int g = row / k, j = row - g * k;
        int idx = sidx[g * k + j];
        int hrow = g * n_old + idx;
        float4 v = *(const float4*)(hbuf + (size_t)hrow * RSTRIDE + c4 * 4);
        *(float4*)&ht[rr * 36 + c4 * 4] = v;
        if (c4 == 0) vals[rr] = score[hrow];
    }
    __syncthreads();
    int lane = threadIdx.x & 63, cg = threadIdx.x >> 6;
    int row = row0 + lane;
    float val = vals[lane];
    const float* hr = &ht[lane * 36];
    const float* wbase = Wc + cg * 15;
    float acc[15];
#pragma unroll
    for (int c = 0; c < 15; ++c) acc[c] = 0.f;
#pragma unroll
    for (int m4 = 0; m4 < 7; ++m4) {
        float4 hq = *(const float4*)(hr + m4 * 4);
        float xs[4] = {hq.x, hq.y, hq.z, hq.w};
#pragma unroll
        for (int u = 0; u < 4; ++u) {
            float xv = xs[u];
            const float* wrow = wbase + (m4 * 4 + u) * 60;   // wave-uniform
#pragma unroll
            for (int c = 0; c < 15; ++c) acc[c] += xv * wrow[c];
        }
    }
    {   // tail m = 28, 29
        float2 h2 = *(const float2*)(hr + 28);
        const float* w28 = wbase + 28 * 60;
        const float* w29 = wbase + 29 * 60;
#pragma unroll
        for (int c = 0; c < 15; ++c)
            acc[c] += h2.x * w28[c] + h2.y * w29[c];
    }
    bool isR = (cg < 2);
    float o[16];
#pragma unroll
    for (int c = 0; c < 15; ++c) {
        float bv = isR ? 0.f : brel[(cg - 2) * 15 + c];
        o[c] = val * acc[c] + bv;
    }
    o[15] = 0.f;
    float4* op = (float4*)(rt + ((size_t)cg * NTOT + row) * 16);
    op[0] = make_float4(o[0], o[1], o[2], o[3]);
    op[1] = make_float4(o[4], o[5], o[6], o[7]);
    op[2] = make_float4(o[8], o[9], o[10], o[11]);
    op[3] = make_float4(o[12], o[13], o[14], o[15]);
}

// ---------------------------------------------------------------------------
// Layer-1 counting sort (the only sort in the pipeline).
// ---------------------------------------------------------------------------
__global__ __launch_bounds__(1024) void k_hist1(
    const int* __restrict__ dst, unsigned short* __restrict__ rank,
    int* __restrict__ chunkCnt)
{
    __shared__ unsigned int cnt[2048];
    int chunk = blockIdx.x, g = chunk >> 2;
    for (int i = threadIdx.x; i < 2048; i += 1024) cnt[i] = 0;
    __syncthreads();
    int e0 = chunk * 8192;
#pragma unroll
    for (int u = 0; u < 8; ++u) {
        int e = e0 + u * 1024 + threadIdx.x;
        int d = dst[e] - g * N0;
        rank[e] = (unsigned short)atomicAdd(&cnt[d], 1u);
    }
    __syncthreads();
    for (int i = threadIdx.x; i < 2048; i += 1024) chunkCnt[chunk * 2048 + i] = cnt[i];
}

__global__ __launch_bounds__(1024) void k_scan(
    int* __restrict__ chunkCnt, int* __restrict__ runStart, int* __restrict__ runLen)
{
    __shared__ int bufA[2048], bufB[2048];
    int g = blockIdx.x;
    int c0[2], c1[2], c2[2], tt[2];
    for (int h2 = 0; h2 < 2; ++h2) {
        int d = threadIdx.x + h2 * 1024;
        c0[h2] = chunkCnt[(g * 4 + 0) * 2048 + d];
        c1[h2] = chunkCnt[(g * 4 + 1) * 2048 + d];
        c2[h2] = chunkCnt[(g * 4 + 2) * 2048 + d];
        int c3 = chunkCnt[(g * 4 + 3) * 2048 + d];
        tt[h2] = c0[h2] + c1[h2] + c2[h2] + c3;
        bufA[d] = tt[h2];
    }
    __syncthreads();
    int* s_ = bufA; int* d_ = bufB;
    for (int off = 1; off < 2048; off <<= 1) {
        for (int h2 = 0; h2 < 2; ++h2) {
            int d = threadIdx.x + h2 * 1024;
            int v = s_[d];
            if (d >= off) v += s_[d - off];
            d_[d] = v;
        }
        __syncthreads();
        int* tmp = s_; s_ = d_; d_ = tmp;
    }
    for (int h2 = 0; h2 < 2; ++h2) {
        int d = threadIdx.x + h2 * 1024;
        int ex = s_[d] - tt[h2];
        runStart[g * 2048 + d] = ex;
        runLen[g * 2048 + d] = tt[h2];
        chunkCnt[(g * 4 + 0) * 2048 + d] = ex;
        chunkCnt[(g * 4 + 1) * 2048 + d] = ex + c0[h2];
        chunkCnt[(g * 4 + 2) * 2048 + d] = ex + c0[h2] + c1[h2];
        chunkCnt[(g * 4 + 3) * 2048 + d] = ex + c0[h2] + c1[h2] + c2[h2];
    }
}

__global__ __launch_bounds__(1024) void k_scat1(
    const int* __restrict__ src, const int* __restrict__ dst, const float* __restrict__ ew,
    const unsigned short* __restrict__ rank, const int* __restrict__ chunkOff,
    float2* __restrict__ sOut)
{
    int chunk = blockIdx.x, g = chunk >> 2;
    int e0 = chunk * 8192;
#pragma unroll
    for (int u = 0; u < 8; ++u) {
        int e = e0 + u * 1024 + threadIdx.x;
        int d = dst[e] - g * N0;
        int pos = chunkOff[chunk * 2048 + d] + (int)rank[e];
        sOut[(size_t)g * ESTRIDE1 + pos] = make_float2(__int_as_float(src[e]), ew[e]);
    }
}

// ---------------------------------------------------------------------------
// Run-major aggregation over the LAYER-1 CSR for ALL layers. Reads rt planes:
// r lane j -> plane (j<15?0:1) offset j%15; t -> plane 2/3. Zero atomics;
// fused +t/relu and score.
// ---------------------------------------------------------------------------
template<int LVL>
__global__ __launch_bounds__(256) void k_gather(
    const float2* __restrict__ sE, const int* __restrict__ runS, const int* __restrict__ runL,
    const int* __restrict__ ind1, const int* __restrict__ ind2, const int* __restrict__ mapc,
    const float* __restrict__ rt, float* __restrict__ h,
    const float* __restrict__ poolw, float* __restrict__ score,
    int n, int rK, int nblocks)
{
    int b = blockIdx.x;
    int cpx = nblocks >> 3;                 // XCD-chunked swizzle
    b = (b & 7) * cpx + (b >> 3);
    int slot = threadIdx.x >> 5, j = threadIdx.x & 31;
    int v = b * 8 + slot;
    int g = v / n;
    int local = v - g * n;
    int v1 = local;
    if (LVL >= 2) v1 = ind2[g * K2 + v1];
    if (LVL >= 1) v1 = ind1[g * K1 + v1];
    int s0 = runS[g * 2048 + v1], len = runL[g * 2048 + v1];
    const float2* meta = sE + (size_t)g * ESTRIDE1 + s0;
    int rbase = g * rK;
    int oj = (j < 15) ? j : ((j < 30) ? j - 15 : 14);
    const float* rplane = rt + ((j < 15) ? 0 : ((size_t)NTOT * 16)) + oj;
    float acc = 0.f;
    for (int c = 0; c < len; c += 8) {
        int lim = len - c; if (lim > 8) lim = 8;
        float2 m[8];
#pragma unroll
        for (int u = 0; u < 8; ++u) m[u] = meta[c + (u < lim ? u : 0)];
        int rowv[8]; float wv[8];
#pragma unroll
        for (int u = 0; u < 8; ++u) {
            int srcg = __float_as_int(m[u].x);
            float w = (u < lim) ? m[u].y : 0.f;
            if (LVL == 0) {
                rowv[u] = srcg;
            } else {
                int ss = mapc[srcg];
                rowv[u] = rbase + (ss < 0 ? 0 : ss);
                w = (ss < 0) ? 0.f : w;
            }
            wv[u] = w;
        }
#pragma unroll
        for (int u = 0; u < 8; ++u)
            acc += rplane[(size_t)rowv[u] * 16] * wv[u];
    }
    float wj = (j < H) ? poolw[j] : 0.f;
    float hval = 0.f;
    if (j < H) {
        size_t tp = (j < 15) ? 2 : 3;
        hval = fmaxf(acc + rt[(tp * NTOT + v) * 16 + oj], 0.f);
        h[(size_t)v * RSTRIDE + j] = hval;
    }
    float p = hval * wj, q = wj * wj;
#pragma unroll
    for (int off = 16; off > 0; off >>= 1) {
        p += __shfl_xor(p, off, 32);
        q += __shfl_xor(q, off, 32);
    }
    if (j == 0) score[v] = tanhf(p / sqrtf(q));
}

// ---------------------------------------------------------------------------
// Top-k (desc score, asc idx; jax.lax.top_k tie-break) + cumulative map.
// ---------------------------------------------------------------------------
__global__ __launch_bounds__(1024) void k_topk_map(
    const float* __restrict__ score, int* __restrict__ sidx, int* __restrict__ mapc,
    int n, int k, int first)
{
    __shared__ unsigned long long keys[2048];
    __shared__ int inv[2048];
    int g = blockIdx.x;
    for (int i = threadIdx.x; i < 2048; i += 1024) {
        unsigned long long key = ~0ull;
        if (i < n) {
            float s = score[g * n + i];
            if (s == 0.f) s = 0.f;                 // canonicalize -0 -> +0
            unsigned u = __float_as_uint(s);
            unsigned asc = (u & 0x80000000u) ? ~u : (u | 0x80000000u);
            unsigned desc = ~asc;
            key = ((unsigned long long)desc << 32) | (unsigned)i;
        }
        keys[i] = key;
        inv[i] = -1;
    }
    __syncthreads();
    for (int kk = 2; kk <= 2048; kk <<= 1) {
        for (int jj = kk >> 1; jj > 0; jj >>= 1) {
            for (int i = threadIdx.x; i < 2048; i += 1024) {
                int ixj = i ^ jj;
                if (ixj > i) {
                    unsigned long long a = keys[i], bb = keys[ixj];
                    bool up = ((i & kk) == 0);
                    if ((a > bb) == up) { keys[i] = bb; keys[ixj] = a; }
                }
            }
            __syncthreads();
        }
    }
    for (int j = threadIdx.x; j < k; j += 1024) {
        int idx = (int)(keys[j] & 0xffffffffu);
        sidx[g * k + j] = idx;
        inv[idx] = j;
    }
    __syncthreads();
    if (first) {
        for (int v = threadIdx.x; v < N0; v += 1024)
            mapc[g * N0 + v] = inv[v];
    } else {
        for (int v = threadIdx.x; v < N0; v += 1024) {
            int m = mapc[g * N0 + v];
            mapc[g * N0 + v] = (m >= 0) ? inv[m] : -1;
        }
    }
}

// ---------------------------------------------------------------------------
// Segmented readout: grid (RSEG, B). Partial [max;sum] over a row slice.
// ---------------------------------------------------------------------------
__global__ __launch_bounds__(256) void k_rpart(
    const float* __restrict__ hbuf, const int* __restrict__ sidx,
    const float* __restrict__ score, float* __restrict__ pmax, float* __restrict__ psum,
    int n_old, int k)
{
    __shared__ float smax[8][32], ssum[8][32];
    int g = blockIdx.y, seg = blockIdx.x;
    int clen = (k + RSEG - 1) / RSEG;
    int start = seg * clen;
    int end = start + clen; if (end > k) end = k;
    int f = threadIdx.x & 31, rr = threadIdx.x >> 5;
    float mx = -INFINITY, sm = 0.f;
    if (f < H) {
        for (int j = start + rr; j < end; j += 8) {
            int idx = sidx[g * k + j];
            float val = score[g * n_old + idx];
            float v = hbuf[(size_t)(g * n_old + idx) * RSTRIDE + f] * val;
            mx = fmaxf(mx, v);
            sm += v;
        }
    }
    smax[rr][f] = mx; ssum[rr][f] = sm;
    __syncthreads();
    if (rr == 0) {
        for (int q = 1; q < 8; ++q) { mx = fmaxf(mx, smax[q][f]); sm += ssum[q][f]; }
        pmax[(g * RSEG + seg) * 32 + f] = mx;
        psum[(g * RSEG + seg) * 32 + f] = sm;
    }
}

// Finalize all 3 readouts + z = relu(x1+x2+x3). grid B, block 64.
__global__ __launch_bounds__(64) void k_zfin(
    const float* __restrict__ pm1, const float* __restrict__ ps1,
    const float* __restrict__ pm2, const float* __restrict__ ps2,
    const float* __restrict__ pm3, const float* __restrict__ ps3,
    float* __restrict__ z)
{
    int g = blockIdx.x, c = threadIdx.x;
    if (c >= 60) return;
    float v1, v2, v3;
    if (c < H) {
        float m1 = -INFINITY, m2 = -INFINITY, m3 = -INFINITY;
        for (int s = 0; s < RSEG; ++s) {
            m1 = fmaxf(m1, pm1[(g * RSEG + s) * 32 + c]);
            m2 = fmaxf(m2, pm2[(g * RSEG + s) * 32 + c]);
            m3 = fmaxf(m3, pm3[(g * RSEG + s) * 32 + c]);
        }
        v1 = m1; v2 = m2; v3 = m3;
    } else {
        int f = c - H;
        float s1 = 0.f, s2 = 0.f, s3 = 0.f;
        for (int s = 0; s < RSEG; ++s) {
            s1 += ps1[(g * RSEG + s) * 32 + f];
            s2 += ps2[(g * RSEG + s) * 32 + f];
            s3 += ps3[(g * RSEG + s) * 32 + f];
        }
        v1 = s1 / (float)K1; v2 = s2 / (float)K2; v3 = s3 / (float)K3;
    }
    z[g * 60 + c] = fmaxf(v1 + v2 + v3, 0.f);
}

// a1[h,b,o] = relu(sum_d z[b,d]*W1[h,d,o] + b1[h,o]),  o<240, d<60
__global__ __launch_bounds__(256) void k_mlp1(
    const float* __restrict__ z, const float* __restrict__ W,
    const float* __restrict__ bias, float* __restrict__ a)
{
    int hb = blockIdx.x, hh = hb >> 6, b = hb & 63;
    __shared__ float zr[60];
    if (threadIdx.x < 60) zr[threadIdx.x] = z[b * 60 + threadIdx.x];
    __syncthreads();
    int o = threadIdx.x;
    if (o < 240) {
        float acc = bias[hh * 240 + o];
        const float* Wp = W + hh * 60 * 240;
#pragma unroll
        for (int d = 0; d < 60; ++d) acc += zr[d] * Wp[d * 240 + o];
        a[(hh * B + b) * 240 + o] = fmaxf(acc, 0.f);
    }
}

// a2 GEMM: grid (11 heads x 15 col-tiles of 64); a1 tile in LDS.
__global__ __launch_bounds__(256) void k_mlp2(
    const float* __restrict__ a1, const float* __restrict__ W,
    const float* __restrict__ bias, float* __restrict__ a2)
{
    __shared__ float a1t[64 * 240];
    int hh = blockIdx.x / 15, ct = blockIdx.x % 15;
    const float4* ag = (const float4*)(a1 + (size_t)hh * B * 240);
    for (int i = threadIdx.x; i < 64 * 240 / 4; i += 256)
        ((float4*)a1t)[i] = ag[i];
    __syncthreads();
    int col = threadIdx.x & 63, rg = threadIdx.x >> 6;
    const float* Wp = W + (size_t)hh * 240 * 960 + ct * 64 + col;
    float acc[16];
#pragma unroll
    for (int i = 0; i < 16; ++i) acc[i] = 0.f;
#pragma unroll 4
    for (int o = 0; o < 240; ++o) {
        float w = Wp[(size_t)o * 960];
        const float* ar = &a1t[0];
#pragma unroll
        for (int i = 0; i < 16; ++i)
            acc[i] += w * ar[(rg * 16 + i) * 240 + o];
    }
    float bv = bias[hh * 960 + ct * 64 + col];
#pragma unroll
    for (int i = 0; i < 16; ++i)
        a2[((size_t)hh * B + rg * 16 + i) * 960 + ct * 64 + col] =
            fmaxf(acc[i] + bv, 0.f);
}

// out[h,b,q] = sum_p a2[h,b,p]*W3[h,p,q] + b3[h,q],  q<8, p<960
__global__ __launch_bounds__(64) void k_mlp3(
    const float* __restrict__ a2, const float* __restrict__ W,
    const float* __restrict__ bias, float* __restrict__ out)
{
    int hb = blockIdx.x, hh = hb >> 6, b = hb & 63;
    __shared__ float ar[960];
    __shared__ float part[64];
    for (int i = threadIdx.x; i < 960; i += 64) ar[i] = a2[(hh * B + b) * 960 + i];
    __syncthreads();
    int q = threadIdx.x & 7, c = threadIdx.x >> 3;
    const float* Wp = W + hh * 960 * 8;
    float acc = 0.f;
    for (int p = c; p < 960; p += 8) acc += ar[p] * Wp[p * 8 + q];
    part[threadIdx.x] = acc;
    __syncthreads();
    if (threadIdx.x < 8) {
        float s = bias[hh * 8 + threadIdx.x];
        for (int cc = 0; cc < 8; ++cc) s += part[cc * 8 + threadIdx.x];
        out[(hh * B + b) * 8 + threadIdx.x] = s;
    }
}

// ---------------------------------------------------------------------------
extern "C" void kernel_launch(void* const* d_in, const int* in_sizes, int n_in,
                              void* d_out, int out_size, void* d_ws, size_t ws_size,
                              hipStream_t stream)
{
    const float* x       = (const float*)d_in[0];
    const int*   eidx    = (const int*)d_in[1];
    const int*   src0    = eidx;
    const int*   dst0    = eidx + ETOT;
    const float* ew0     = (const float*)d_in[2];
    const float* ln_g    = (const float*)d_in[4];
    const float* ln_b    = (const float*)d_in[5];
    const float* W_rel1  = (const float*)d_in[6];
    const float* b_rel1  = (const float*)d_in[7];
    const float* W_root1 = (const float*)d_in[8];
    const float* W_rel2  = (const float*)d_in[9];
    const float* b_rel2  = (const float*)d_in[10];
    const float* W_root2 = (const float*)d_in[11];
    const float* W_rel3  = (const float*)d_in[12];
    const float* b_rel3  = (const float*)d_in[13];
    const float* W_root3 = (const float*)d_in[14];
    const float* pool_w1 = (const float*)d_in[15];
    const float* pool_w2 = (const float*)d_in[16];
    const float* pool_w3 = (const float*)d_in[17];
    const float* head_W1 = (const float*)d_in[18];
    const float* head_b1 = (const float*)d_in[19];
    const float* head_W2 = (const float*)d_in[20];
    const float* head_b2 = (const float*)d_in[21];
    const float* head_W3 = (const float*)d_in[22];
    const float* head_b3 = (const float*)d_in[23];

    // ---- workspace carve (~72 MB) ----
    float* ws     = (float*)d_ws;
    float* rtbuf  = ws;                               // 4 planes x NTOT x 16
    float* abuf   = rtbuf + (size_t)NTOT * 64;        // NTOT*32 (h)
    float2* sA    = (float2*)(abuf + (size_t)NTOT * RSTRIDE); // B*ESTRIDE1
    float* score  = (float*)(sA + (size_t)B * ESTRIDE1);      // NTOT
    int*   sidxA  = (int*)(score + NTOT);             // B*K1
    int*   sidxB  = sidxA + B * K1;                   // B*K2
    int*   sidxC  = sidxB + B * K2;                   // B*K3
    int*   mapc   = sidxC + B * K3;                   // NTOT
    int*   runSA  = mapc + NTOT;                      // B*2048
    int*   runLA  = runSA + B * 2048;                 // B*2048
    float* pm1    = (float*)(runLA + B * 2048);       // B*RSEG*32 each
    float* ps1    = pm1 + B * RSEG * 32;
    float* pm2    = ps1 + B * RSEG * 32;
    float* ps2    = pm2 + B * RSEG * 32;
    float* pm3    = ps2 + B * RSEG * 32;
    float* ps3    = pm3 + B * RSEG * 32;
    float* zb     = ps3 + B * RSEG * 32;              // B*60
    float* Wc1    = zb + B * 60;                      // 128*60
    float* S1     = Wc1 + IN_DIM * 60;
    float* T1     = S1 + 60;
    float* Wc2    = T1 + 60;                          // 30*60
    float* Wc3    = Wc2 + H * 60;
    // aliases into abuf (dead before gather<0>): chunk counters + edge ranks
    int* chunkBuf         = (int*)abuf;                                  // 256*2048 ints
    unsigned short* rank  = (unsigned short*)((char*)abuf + (4u << 20)); // ETOT u16
    // heads alias rtbuf (dead after layer-3 gather)
    float* a1 = rtbuf;
    float* a2 = a1 + NH * B * 240;

    k_prep<<<1, 256, 0, stream>>>(ln_g, ln_b, W_rel1, b_rel1, W_root1,
                                  W_rel2, W_root2, W_rel3, W_root3,
                                  Wc1, S1, T1, Wc2, Wc3);

    // ---- layer-1 CSR (the only sort) ----
    k_hist1<<<256, 1024, 0, stream>>>(dst0, rank, chunkBuf);
    k_scan<<<B, 1024, 0, stream>>>(chunkBuf, runSA, runLA);
    k_scat1<<<256, 1024, 0, stream>>>(src0, dst0, ew0, rank, chunkBuf, sA);

    // ---- layer 1 ----
    k_lnproj<<<NTOT / 64, 256, 0, stream>>>(x, Wc1, S1, T1, rtbuf);
    k_gather<0><<<NTOT / 8, 256, 0, stream>>>(sA, runSA, runLA, nullptr, nullptr, nullptr,
                                              rtbuf, abuf, pool_w1, score,
                                              N0, N0, NTOT / 8);
    k_topk_map<<<B, 1024, 0, stream>>>(score, sidxA, mapc, N0, K1, 1);
    k_rpart<<<dim3(RSEG, B), 256, 0, stream>>>(abuf, sidxA, score, pm1, ps1, N0, K1);
    k_proj30p<<<B * K1 / 64, 256, 0, stream>>>(abuf, sidxA, score, Wc2, b_rel2,
                                               rtbuf, N0, K1);

    // ---- layer 2 (no sort: reuse layer-1 runs via sidxA + mapc filter) ----
    k_gather<1><<<B * K1 / 8, 256, 0, stream>>>(sA, runSA, runLA, sidxA, nullptr, mapc,
                                                rtbuf, abuf, pool_w2, score,
                                                K1, K1, B * K1 / 8);
    k_topk_map<<<B, 1024, 0, stream>>>(score, sidxB, mapc, K1, K2, 0);
    k_rpart<<<dim3(RSEG, B), 256, 0, stream>>>(abuf, sidxB, score, pm2, ps2, K1, K2);
    k_proj30p<<<B * K2 / 64, 256, 0, stream>>>(abuf, sidxB, score, Wc3, b_rel3,
                                               rtbuf, K1, K2);

    // ---- layer 3 ----
    k_gather<2><<<B * K2 / 8, 256, 0, stream>>>(sA, runSA, runLA, sidxA, sidxB, mapc,
                                                rtbuf, abuf, pool_w3, score,
                                                K2, K2, B * K2 / 8);
    k_topk_map<<<B, 1024, 0, stream>>>(score, sidxC, mapc, K2, K3, 0);
    k_rpart<<<dim3(RSEG, B), 256, 0, stream>>>(abuf, sidxC, score, pm3, ps3, K2, K3);

    // ---- heads ----
    k_zfin<<<B, 64, 0, stream>>>(pm1, ps1, pm2, ps2, pm3, ps3, zb);
    k_mlp1<<<NH * B, 256, 0, stream>>>(zb, head_W1, head_b1, a1);
    k_mlp2<<<NH * 15, 256, 0, stream>>>(a1, head_W2, head_b2, a2);
    k_mlp3<<<NH * B, 64, 0, stream>>>(a2, head_W3, head_b3, (float*)d_out);
}

// Round 13
// 634.285 us; speedup vs baseline: 1.0994x; 1.0994x over previous
//
#include <hip/hip_runtime.h>
#include <hip/hip_bf16.h>

#define B 64
#define N0 2048
#define DEG 16
#define IN_DIM 128
#define H 30
#define NH 11
#define K1 1844
#define K2 1660
#define K3 1494
#define NTOT (B * N0)        /* 131072 */
#define ETOT (NTOT * DEG)    /* 2097152 */
#define RSTRIDE 32           /* row stride for h */
#define ESTRIDE1 32768       /* layer-1 CSR capacity per graph */
#define RSEG 16              /* readout segments per graph */
/* rt layout: 4 planes [NTOT][16]; plane cg holds combined cols cg*15..cg*15+14
   (cg 0,1 = r cols 0-29; cg 2,3 = t cols 0-29). 16th col = pad -> every
   thread-store is one full aligned 64B line. */

// ---------------------------------------------------------------------------
// Prep: fold layernorm gamma into layer-1 weights; combine rel/root weights.
// ---------------------------------------------------------------------------
__global__ __launch_bounds__(256) void k_prep(
    const float* __restrict__ ln_g, const float* __restrict__ ln_b,
    const float* __restrict__ Wrel1, const float* __restrict__ brel1, const float* __restrict__ Wroot1,
    const float* __restrict__ Wrel2, const float* __restrict__ Wroot2,
    const float* __restrict__ Wrel3, const float* __restrict__ Wroot3,
    float* __restrict__ Wc1, float* __restrict__ S1, float* __restrict__ T1,
    float* __restrict__ Wc2, float* __restrict__ Wc3)
{
    int tid = threadIdx.x;
    for (int i = tid; i < IN_DIM * 60; i += 256) {
        int j = i / 60, c = i - j * 60;
        float w = (c < H) ? Wrel1[j * H + c] : Wroot1[j * H + (c - H)];
        Wc1[i] = w * ln_g[j];
    }
    if (tid < 60) {
        int c = tid;
        float s = 0.f, tt = 0.f;
        for (int j = 0; j < IN_DIM; ++j) {
            float w = (c < H) ? Wrel1[j * H + c] : Wroot1[j * H + (c - H)];
            s += w * ln_g[j];
            tt += w * ln_b[j];
        }
        S1[c] = s;
        T1[c] = (c < H) ? tt : tt + brel1[c - H];
    }
    for (int i = tid; i < H * 60; i += 256) {
        int j = i / 60, c = i - j * 60;
        Wc2[i] = (c < H) ? Wrel2[j * H + c] : Wroot2[j * H + (c - H)];
        Wc3[i] = (c < H) ? Wrel3[j * H + c] : Wroot3[j * H + (c - H)];
    }
}

// ---------------------------------------------------------------------------
// Layer 1 LN+proj v10: block = 64-row x tile in LDS (coalesced stage) + W
// slice in LDS [128][4][16] read via broadcast ds_read_b128 (4 per k).
// r6/r11/r12 triangulation: W must be on the VECTOR (LDS) path -- the
// wave-uniform global reads became s_loads that thrash the scalar cache
// (r11 100us, r12 146us vs r6 66us). Wave w = col-group w, lane = row.
// ---------------------------------------------------------------------------
__global__ __launch_bounds__(256) void k_lnproj(
    const float* __restrict__ x, const float* __restrict__ Wc,
    const float* __restrict__ S, const float* __restrict__ T,
    float* __restrict__ rt)
{
    __shared__ float xt[64 * 132];             // 64 rows, stride 132 (pad)
    __shared__ float wlds[IN_DIM][4][16];      // [k][cg][15+pad], b128-aligned
    int row0 = blockIdx.x * 64;
    const float4* xg = (const float4*)(x + (size_t)row0 * IN_DIM);
#pragma unroll
    for (int q = 0; q < 8; ++q) {
        int i = q * 256 + threadIdx.x;         // 0..2047 float4 of the tile
        float4 v = xg[i];
        int r = i >> 5, c4 = i & 31;
        *(float4*)&xt[r * 132 + c4 * 4] = v;
    }
    for (int i = threadIdx.x; i < IN_DIM * 64; i += 256) {
        int k = i >> 6, c = i & 63;
        int cgg = c >> 4, j = c & 15;
        wlds[k][cgg][j] = (j < 15) ? Wc[k * 60 + cgg * 15 + j] : 0.f;
    }
    __syncthreads();
    int lane = threadIdx.x & 63, cg = threadIdx.x >> 6;
    int row = row0 + lane;
    const float* xr = &xt[lane * 132];
    float acc[15];
#pragma unroll
    for (int c = 0; c < 15; ++c) acc[c] = 0.f;
    float sum = 0.f, sumsq = 0.f;
    for (int k4 = 0; k4 < 32; ++k4) {
        float4 xq = *(const float4*)(xr + k4 * 4);
        float xs[4] = {xq.x, xq.y, xq.z, xq.w};
#pragma unroll
        for (int u = 0; u < 4; ++u) {
            int k = k4 * 4 + u;
            float xv = xs[u];
            sum += xv; sumsq += xv * xv;
            float4 w0 = *(const float4*)&wlds[k][cg][0];    // broadcast reads
            float4 w1 = *(const float4*)&wlds[k][cg][4];
            float4 w2 = *(const float4*)&wlds[k][cg][8];
            float4 w3 = *(const float4*)&wlds[k][cg][12];   // .w is pad
            acc[0]  += xv * w0.x; acc[1]  += xv * w0.y;
            acc[2]  += xv * w0.z; acc[3]  += xv * w0.w;
            acc[4]  += xv * w1.x; acc[5]  += xv * w1.y;
            acc[6]  += xv * w1.z; acc[7]  += xv * w1.w;
            acc[8]  += xv * w2.x; acc[9]  += xv * w2.y;
            acc[10] += xv * w2.z; acc[11] += xv * w2.w;
            acc[12] += xv * w3.x; acc[13] += xv * w3.y;
            acc[14] += xv * w3.z;
        }
    }
    float mean = sum * (1.f / 128.f);
    float var = sumsq * (1.f / 128.f) - mean * mean;
    float rstd = 1.0f / sqrtf(var + 1e-5f);
    int scol = cg * 15;
    float o[16];
#pragma unroll
    for (int c = 0; c < 15; ++c)
        o[c] = rstd * (acc[c] - mean * S[scol + c]) + T[scol + c];
    o[15] = 0.f;
    float4* op = (float4*)(rt + ((size_t)cg * NTOT + row) * 16);
    op[0] = make_float4(o[0], o[1], o[2], o[3]);
    op[1] = make_float4(o[4], o[5], o[6], o[7]);
    op[2] = make_float4(o[8], o[9], o[10], o[11]);
    op[3] = make_float4(o[12], o[13], o[14], o[15]);
}

// ---------------------------------------------------------------------------
// Pooled projection v6 (layers 2/3): 64 gathered h-rows staged in LDS + W
// slice in LDS [30][4][16] (broadcast b128 reads, not s_load).
// ---------------------------------------------------------------------------
__global__ __launch_bounds__(256) void k_proj30p(
    const float* __restrict__ hbuf, const int* __restrict__ sidx,
    const float* __restrict__ score, const float* __restrict__ Wc,
    const float* __restrict__ brel, float* __restrict__ rt,
    int n_old, int k)
{
    __shared__ float ht[64 * 36];              // 64 rows x 32 (+4 pad)
    __shared__ float vals[64];
    __shared__ float wlds[H][4][16];
    int row0 = blockIdx.x * 64;
#pragma unroll
    for (int q = 0; q < 2; ++q) {
        int i = q * 256 + threadIdx.x;         // 0..511: (row, c4)
        int rr = i >> 3, c4 = i & 7;
        int row = row0 + rr;
        int g = row / k, j = row - g * k;
        int idx = sidx[g * k + j];
        int hrow = g * n_old + idx;
        float4 v = *(const float4*)(hbuf + (size_t)hrow * RSTRIDE + c4 * 4);
        *(float4*)&ht[rr * 36 + c4 * 4] = v;
        if (c4 == 0) vals[rr] = score[hrow];
    }
    for (int i = threadIdx.x; i < H * 64; i += 256) {
        int m = i >> 6, c = i & 63;
        int cgg = c >> 4, j = c & 15;
        wlds[m][cgg][j] = (j < 15) ? Wc[m * 60 + cgg * 15 + j] : 0.f;
    }
    __syncthreads();
    int lane = threadIdx.x & 63, cg = threadIdx.x >> 6;
    int row = row0 + lane;
    float val = vals[lane];
    const float* hr = &ht[lane * 36];
    float acc[15];
#pragma unroll
    for (int c = 0; c < 15; ++c) acc[c] = 0.f;
#pragma unroll
    for (int m4 = 0; m4 < 8; ++m4) {           // 30 ks: last quad has 2
        float4 hq = *(const float4*)(hr + m4 * 4);
        float xs[4] = {hq.x, hq.y, hq.z, hq.w};
        int lim = (m4 == 7) ? 2 : 4;
        for (int u = 0; u < lim; ++u) {
            int m = m4 * 4 + u;
            float xv = xs[u];
            float4 w0 = *(const float4*)&wlds[m][cg][0];
            float4 w1 = *(const float4*)&wlds[m][cg][4];
            float4 w2 = *(const float4*)&wlds[m][cg][8];
            float4 w3 = *(const float4*)&wlds[m][cg][12];
            acc[0]  += xv * w0.x; acc[1]  += xv * w0.y;
            acc[2]  += xv * w0.z; acc[3]  += xv * w0.w;
            acc[4]  += xv * w1.x; acc[5]  += xv * w1.y;
            acc[6]  += xv * w1.z; acc[7]  += xv * w1.w;
            acc[8]  += xv * w2.x; acc[9]  += xv * w2.y;
            acc[10] += xv * w2.z; acc[11] += xv * w2.w;
            acc[12] += xv * w3.x; acc[13] += xv * w3.y;
            acc[14] += xv * w3.z;
        }
    }
    bool isR = (cg < 2);
    float o[16];
#pragma unroll
    for (int c = 0; c < 15; ++c) {
        float bv = isR ? 0.f : brel[(cg - 2) * 15 + c];
        o[c] = val * acc[c] + bv;
    }
    o[15] = 0.f;
    float4* op = (float4*)(rt + ((size_t)cg * NTOT + row) * 16);
    op[0] = make_float4(o[0], o[1], o[2], o[3]);
    op[1] = make_float4(o[4], o[5], o[6], o[7]);
    op[2] = make_float4(o[8], o[9], o[10], o[11]);
    op[3] = make_float4(o[12], o[13], o[14], o[15]);
}

// ---------------------------------------------------------------------------
// Layer-1 counting sort (the only sort in the pipeline).
// ---------------------------------------------------------------------------
__global__ __launch_bounds__(1024) void k_hist1(
    const int* __restrict__ dst, unsigned short* __restrict__ rank,
    int* __restrict__ chunkCnt)
{
    __shared__ unsigned int cnt[2048];
    int chunk = blockIdx.x, g = chunk >> 2;
    for (int i = threadIdx.x; i < 2048; i += 1024) cnt[i] = 0;
    __syncthreads();
    int e0 = chunk * 8192;
#pragma unroll
    for (int u = 0; u < 8; ++u) {
        int e = e0 + u * 1024 + threadIdx.x;
        int d = dst[e] - g * N0;
        rank[e] = (unsigned short)atomicAdd(&cnt[d], 1u);
    }
    __syncthreads();
    for (int i = threadIdx.x; i < 2048; i += 1024) chunkCnt[chunk * 2048 + i] = cnt[i];
}

__global__ __launch_bounds__(1024) void k_scan(
    int* __restrict__ chunkCnt, int* __restrict__ runStart, int* __restrict__ runLen)
{
    __shared__ int bufA[2048], bufB[2048];
    int g = blockIdx.x;
    int c0[2], c1[2], c2[2], tt[2];
    for (int h2 = 0; h2 < 2; ++h2) {
        int d = threadIdx.x + h2 * 1024;
        c0[h2] = chunkCnt[(g * 4 + 0) * 2048 + d];
        c1[h2] = chunkCnt[(g * 4 + 1) * 2048 + d];
        c2[h2] = chunkCnt[(g * 4 + 2) * 2048 + d];
        int c3 = chunkCnt[(g * 4 + 3) * 2048 + d];
        tt[h2] = c0[h2] + c1[h2] + c2[h2] + c3;
        bufA[d] = tt[h2];
    }
    __syncthreads();
    int* s_ = bufA; int* d_ = bufB;
    for (int off = 1; off < 2048; off <<= 1) {
        for (int h2 = 0; h2 < 2; ++h2) {
            int d = threadIdx.x + h2 * 1024;
            int v = s_[d];
            if (d >= off) v += s_[d - off];
            d_[d] = v;
        }
        __syncthreads();
        int* tmp = s_; s_ = d_; d_ = tmp;
    }
    for (int h2 = 0; h2 < 2; ++h2) {
        int d = threadIdx.x + h2 * 1024;
        int ex = s_[d] - tt[h2];
        runStart[g * 2048 + d] = ex;
        runLen[g * 2048 + d] = tt[h2];
        chunkCnt[(g * 4 + 0) * 2048 + d] = ex;
        chunkCnt[(g * 4 + 1) * 2048 + d] = ex + c0[h2];
        chunkCnt[(g * 4 + 2) * 2048 + d] = ex + c0[h2] + c1[h2];
        chunkCnt[(g * 4 + 3) * 2048 + d] = ex + c0[h2] + c1[h2] + c2[h2];
    }
}

__global__ __launch_bounds__(1024) void k_scat1(
    const int* __restrict__ src, const int* __restrict__ dst, const float* __restrict__ ew,
    const unsigned short* __restrict__ rank, const int* __restrict__ chunkOff,
    float2* __restrict__ sOut)
{
    int chunk = blockIdx.x, g = chunk >> 2;
    int e0 = chunk * 8192;
#pragma unroll
    for (int u = 0; u < 8; ++u) {
        int e = e0 + u * 1024 + threadIdx.x;
        int d = dst[e] - g * N0;
        int pos = chunkOff[chunk * 2048 + d] + (int)rank[e];
        sOut[(size_t)g * ESTRIDE1 + pos] = make_float2(__int_as_float(src[e]), ew[e]);
    }
}

// ---------------------------------------------------------------------------
// Run-major aggregation over the LAYER-1 CSR for ALL layers. Reads rt planes:
// r lane j -> plane (j<15?0:1) offset j%15; t -> plane 2/3. Zero atomics;
// fused +t/relu and score.
// ---------------------------------------------------------------------------
template<int LVL>
__global__ __launch_bounds__(256) void k_gather(
    const float2* __restrict__ sE, const int* __restrict__ runS, const int* __restrict__ runL,
    const int* __restrict__ ind1, const int* __restrict__ ind2, const int* __restrict__ mapc,
    const float* __restrict__ rt, float* __restrict__ h,
    const float* __restrict__ poolw, float* __restrict__ score,
    int n, int rK, int nblocks)
{
    int b = blockIdx.x;
    int cpx = nblocks >> 3;                 // XCD-chunked swizzle
    b = (b & 7) * cpx + (b >> 3);
    int slot = threadIdx.x >> 5, j = threadIdx.x & 31;
    int v = b * 8 + slot;
    int g = v / n;
    int local = v - g * n;
    int v1 = local;
    if (LVL >= 2) v1 = ind2[g * K2 + v1];
    if (LVL >= 1) v1 = ind1[g * K1 + v1];
    int s0 = runS[g * 2048 + v1], len = runL[g * 2048 + v1];
    const float2* meta = sE + (size_t)g * ESTRIDE1 + s0;
    int rbase = g * rK;
    int oj = (j < 15) ? j : ((j < 30) ? j - 15 : 14);
    const float* rplane = rt + ((j < 15) ? 0 : ((size_t)NTOT * 16)) + oj;
    float acc = 0.f;
    for (int c = 0; c < len; c += 8) {
        int lim = len - c; if (lim > 8) lim = 8;
        float2 m[8];
#pragma unroll
        for (int u = 0; u < 8; ++u) m[u] = meta[c + (u < lim ? u : 0)];
        int rowv[8]; float wv[8];
#pragma unroll
        for (int u = 0; u < 8; ++u) {
            int srcg = __float_as_int(m[u].x);
            float w = (u < lim) ? m[u].y : 0.f;
            if (LVL == 0) {
                rowv[u] = srcg;
            } else {
                int ss = mapc[srcg];
                rowv[u] = rbase + (ss < 0 ? 0 : ss);
                w = (ss < 0) ? 0.f : w;
            }
            wv[u] = w;
        }
#pragma unroll
        for (int u = 0; u < 8; ++u)
            acc += rplane[(size_t)rowv[u] * 16] * wv[u];
    }
    float wj = (j < H) ? poolw[j] : 0.f;
    float hval = 0.f;
    if (j < H) {
        size_t tp = (j < 15) ? 2 : 3;
        hval = fmaxf(acc + rt[(tp * NTOT + v) * 16 + oj], 0.f);
        h[(size_t)v * RSTRIDE + j] = hval;
    }
    float p = hval * wj, q = wj * wj;
#pragma unroll
    for (int off = 16; off > 0; off >>= 1) {
        p += __shfl_xor(p, off, 32);
        q += __shfl_xor(q, off, 32);
    }
    if (j == 0) score[v] = tanhf(p / sqrtf(q));
}

// ---------------------------------------------------------------------------
// Top-k (desc score, asc idx; jax.lax.top_k tie-break) + cumulative map.
// ---------------------------------------------------------------------------
__global__ __launch_bounds__(1024) void k_topk_map(
    const float* __restrict__ score, int* __restrict__ sidx, int* __restrict__ mapc,
    int n, int k, int first)
{
    __shared__ unsigned long long keys[2048];
    __shared__ int inv[2048];
    int g = blockIdx.x;
    for (int i = threadIdx.x; i < 2048; i += 1024) {
        unsigned long long key = ~0ull;
        if (i < n) {
            float s = score[g * n + i];
            if (s == 0.f) s = 0.f;                 // canonicalize -0 -> +0
            unsigned u = __float_as_uint(s);
            unsigned asc = (u & 0x80000000u) ? ~u : (u | 0x80000000u);
            unsigned desc = ~asc;
            key = ((unsigned long long)desc << 32) | (unsigned)i;
        }
        keys[i] = key;
        inv[i] = -1;
    }
    __syncthreads();
    for (int kk = 2; kk <= 2048; kk <<= 1) {
        for (int jj = kk >> 1; jj > 0; jj >>= 1) {
            for (int i = threadIdx.x; i < 2048; i += 1024) {
                int ixj = i ^ jj;
                if (ixj > i) {
                    unsigned long long a = keys[i], bb = keys[ixj];
                    bool up = ((i & kk) == 0);
                    if ((a > bb) == up) { keys[i] = bb; keys[ixj] = a; }
                }
            }
            __syncthreads();
        }
    }
    for (int j = threadIdx.x; j < k; j += 1024) {
        int idx = (int)(keys[j] & 0xffffffffu);
        sidx[g * k + j] = idx;
        inv[idx] = j;
    }
    __syncthreads();
    if (first) {
        for (int v = threadIdx.x; v < N0; v += 1024)
            mapc[g * N0 + v] = inv[v];
    } else {
        for (int v = threadIdx.x; v < N0; v += 1024) {
            int m = mapc[g * N0 + v];
            mapc[g * N0 + v] = (m >= 0) ? inv[m] : -1;
        }
    }
}

// ---------------------------------------------------------------------------
// Segmented readout: grid (RSEG, B). Partial [max;sum] over a row slice.
// ---------------------------------------------------------------------------
__global__ __launch_bounds__(256) void k_rpart(
    const float* __restrict__ hbuf, const int* __restrict__ sidx,
    const float* __restrict__ score, float* __restrict__ pmax, float* __restrict__ psum,
    int n_old, int k)
{
    __shared__ float smax[8][32], ssum[8][32];
    int g = blockIdx.y, seg = blockIdx.x;
    int clen = (k + RSEG - 1) / RSEG;
    int start = seg * clen;
    int end = start + clen; if (end > k) end = k;
    int f = threadIdx.x & 31, rr = threadIdx.x >> 5;
    float mx = -INFINITY, sm = 0.f;
    if (f < H) {
        for (int j = start + rr; j < end; j += 8) {
            int idx = sidx[g * k + j];
            float val = score[g * n_old + idx];
            float v = hbuf[(size_t)(g * n_old + idx) * RSTRIDE + f] * val;
            mx = fmaxf(mx, v);
            sm += v;
        }
    }
    smax[rr][f] = mx; ssum[rr][f] = sm;
    __syncthreads();
    if (rr == 0) {
        for (int q = 1; q < 8; ++q) { mx = fmaxf(mx, smax[q][f]); sm += ssum[q][f]; }
        pmax[(g * RSEG + seg) * 32 + f] = mx;
        psum[(g * RSEG + seg) * 32 + f] = sm;
    }
}

// Finalize all 3 readouts + z = relu(x1+x2+x3). grid B, block 64.
__global__ __launch_bounds__(64) void k_zfin(
    const float* __restrict__ pm1, const float* __restrict__ ps1,
    const float* __restrict__ pm2, const float* __restrict__ ps2,
    const float* __restrict__ pm3, const float* __restrict__ ps3,
    float* __restrict__ z)
{
    int g = blockIdx.x, c = threadIdx.x;
    if (c >= 60) return;
    float v1, v2, v3;
    if (c < H) {
        float m1 = -INFINITY, m2 = -INFINITY, m3 = -INFINITY;
        for (int s = 0; s < RSEG; ++s) {
            m1 = fmaxf(m1, pm1[(g * RSEG + s) * 32 + c]);
            m2 = fmaxf(m2, pm2[(g * RSEG + s) * 32 + c]);
            m3 = fmaxf(m3, pm3[(g * RSEG + s) * 32 + c]);
        }
        v1 = m1; v2 = m2; v3 = m3;
    } else {
        int f = c - H;
        float s1 = 0.f, s2 = 0.f, s3 = 0.f;
        for (int s = 0; s < RSEG; ++s) {
            s1 += ps1[(g * RSEG + s) * 32 + f];
            s2 += ps2[(g * RSEG + s) * 32 + f];
            s3 += ps3[(g * RSEG + s) * 32 + f];
        }
        v1 = s1 / (float)K1; v2 = s2 / (float)K2; v3 = s3 / (float)K3;
    }
    z[g * 60 + c] = fmaxf(v1 + v2 + v3, 0.f);
}

// a1[h,b,o] = relu(sum_d z[b,d]*W1[h,d,o] + b1[h,o]),  o<240, d<60
__global__ __launch_bounds__(256) void k_mlp1(
    const float* __restrict__ z, const float* __restrict__ W,
    const float* __restrict__ bias, float* __restrict__ a)
{
    int hb = blockIdx.x, hh = hb >> 6, b = hb & 63;
    __shared__ float zr[60];
    if (threadIdx.x < 60) zr[threadIdx.x] = z[b * 60 + threadIdx.x];
    __syncthreads();
    int o = threadIdx.x;
    if (o < 240) {
        float acc = bias[hh * 240 + o];
        const float* Wp = W + hh * 60 * 240;
#pragma unroll
        for (int d = 0; d < 60; ++d) acc += zr[d] * Wp[d * 240 + o];
        a[(hh * B + b) * 240 + o] = fmaxf(acc, 0.f);
    }
}

// a2 GEMM: grid (11 heads x 15 col-tiles of 64); a1 tile in LDS.
__global__ __launch_bounds__(256) void k_mlp2(
    const float* __restrict__ a1, const float* __restrict__ W,
    const float* __restrict__ bias, float* __restrict__ a2)
{
    __shared__ float a1t[64 * 240];
    int hh = blockIdx.x / 15, ct = blockIdx.x % 15;
    const float4* ag = (const float4*)(a1 + (size_t)hh * B * 240);
    for (int i = threadIdx.x; i < 64 * 240 / 4; i += 256)
        ((float4*)a1t)[i] = ag[i];
    __syncthreads();
    int col = threadIdx.x & 63, rg = threadIdx.x >> 6;
    const float* Wp = W + (size_t)hh * 240 * 960 + ct * 64 + col;
    float acc[16];
#pragma unroll
    for (int i = 0; i < 16; ++i) acc[i] = 0.f;
#pragma unroll 4
    for (int o = 0; o < 240; ++o) {
        float w = Wp[(size_t)o * 960];
        const float* ar = &a1t[0];
#pragma unroll
        for (int i = 0; i < 16; ++i)
            acc[i] += w * ar[(rg * 16 + i) * 240 + o];
    }
    float bv = bias[hh * 960 + ct * 64 + col];
#pragma unroll
    for (int i = 0; i < 16; ++i)
        a2[((size_t)hh * B + rg * 16 + i) * 960 + ct * 64 + col] =
            fmaxf(acc[i] + bv, 0.f);
}

// out[h,b,q] = sum_p a2[h,b,p]*W3[h,p,q] + b3[h,q],  q<8, p<960
__global__ __launch_bounds__(64) void k_mlp3(
    const float* __restrict__ a2, const float* __restrict__ W,
    const float* __restrict__ bias, float* __restrict__ out)
{
    int hb = blockIdx.x, hh = hb >> 6, b = hb & 63;
    __shared__ float ar[960];
    __shared__ float part[64];
    for (int i = threadIdx.x; i < 960; i += 64) ar[i] = a2[(hh * B + b) * 960 + i];
    __syncthreads();
    int q = threadIdx.x & 7, c = threadIdx.x >> 3;
    const float* Wp = W + hh * 960 * 8;
    float acc = 0.f;
    for (int p = c; p < 960; p += 8) acc += ar[p] * Wp[p * 8 + q];
    part[threadIdx.x] = acc;
    __syncthreads();
    if (threadIdx.x < 8) {
        float s = bias[hh * 8 + threadIdx.x];
        for (int cc = 0; cc < 8; ++cc) s += part[cc * 8 + threadIdx.x];
        out[(hh * B + b) * 8 + threadIdx.x] = s;
    }
}

// ---------------------------------------------------------------------------
extern "C" void kernel_launch(void* const* d_in, const int* in_sizes, int n_in,
                              void* d_out, int out_size, void* d_ws, size_t ws_size,
                              hipStream_t stream)
{
    const float* x       = (const float*)d_in[0];
    const int*   eidx    = (const int*)d_in[1];
    const int*   src0    = eidx;
    const int*   dst0    = eidx + ETOT;
    const float* ew0     = (const float*)d_in[2];
    const float* ln_g    = (const float*)d_in[4];
    const float* ln_b    = (const float*)d_in[5];
    const float* W_rel1  = (const float*)d_in[6];
    const float* b_rel1  = (const float*)d_in[7];
    const float* W_root1 = (const float*)d_in[8];
    const float* W_rel2  = (const float*)d_in[9];
    const float* b_rel2  = (const float*)d_in[10];
    const float* W_root2 = (const float*)d_in[11];
    const float* W_rel3  = (const float*)d_in[12];
    const float* b_rel3  = (const float*)d_in[13];
    const float* W_root3 = (const float*)d_in[14];
    const float* pool_w1 = (const float*)d_in[15];
    const float* pool_w2 = (const float*)d_in[16];
    const float* pool_w3 = (const float*)d_in[17];
    const float* head_W1 = (const float*)d_in[18];
    const float* head_b1 = (const float*)d_in[19];
    const float* head_W2 = (const float*)d_in[20];
    const float* head_b2 = (const float*)d_in[21];
    const float* head_W3 = (const float*)d_in[22];
    const float* head_b3 = (const float*)d_in[23];

    // ---- workspace carve (~72 MB) ----
    float* ws     = (float*)d_ws;
    float* rtbuf  = ws;                               // 4 planes x NTOT x 16
    float* abuf   = rtbuf + (size_t)NTOT * 64;        // NTOT*32 (h)
    float2* sA    = (float2*)(abuf + (size_t)NTOT * RSTRIDE); // B*ESTRIDE1
    float* score  = (float*)(sA + (size_t)B * ESTRIDE1);      // NTOT
    int*   sidxA  = (int*)(score + NTOT);             // B*K1
    int*   sidxB  = sidxA + B * K1;                   // B*K2
    int*   sidxC  = sidxB + B * K2;                   // B*K3
    int*   mapc   = sidxC + B * K3;                   // NTOT
    int*   runSA  = mapc + NTOT;                      // B*2048
    int*   runLA  = runSA + B * 2048;                 // B*2048
    float* pm1    = (float*)(runLA + B * 2048);       // B*RSEG*32 each
    float* ps1    = pm1 + B * RSEG * 32;
    float* pm2    = ps1 + B * RSEG * 32;
    float* ps2    = pm2 + B * RSEG * 32;
    float* pm3    = ps2 + B * RSEG * 32;
    float* ps3    = pm3 + B * RSEG * 32;
    float* zb     = ps3 + B * RSEG * 32;              // B*60
    float* Wc1    = zb + B * 60;                      // 128*60
    float* S1     = Wc1 + IN_DIM * 60;
    float* T1     = S1 + 60;
    float* Wc2    = T1 + 60;                          // 30*60
    float* Wc3    = Wc2 + H * 60;
    // aliases into abuf (dead before gather<0>): chunk counters + edge ranks
    int* chunkBuf         = (int*)abuf;                                  // 256*2048 ints
    unsigned short* rank  = (unsigned short*)((char*)abuf + (4u << 20)); // ETOT u16
    // heads alias rtbuf (dead after layer-3 gather)
    float* a1 = rtbuf;
    float* a2 = a1 + NH * B * 240;

    k_prep<<<1, 256, 0, stream>>>(ln_g, ln_b, W_rel1, b_rel1, W_root1,
                                  W_rel2, W_root2, W_rel3, W_root3,
                                  Wc1, S1, T1, Wc2, Wc3);

    // ---- layer-1 CSR (the only sort) ----
    k_hist1<<<256, 1024, 0, stream>>>(dst0, rank, chunkBuf);
    k_scan<<<B, 1024, 0, stream>>>(chunkBuf, runSA, runLA);
    k_scat1<<<256, 1024, 0, stream>>>(src0, dst0, ew0, rank, chunkBuf, sA);

    // ---- layer 1 ----
    k_lnproj<<<NTOT / 64, 256, 0, stream>>>(x, Wc1, S1, T1, rtbuf);
    k_gather<0><<<NTOT / 8, 256, 0, stream>>>(sA, runSA, runLA, nullptr, nullptr, nullptr,
                                              rtbuf, abuf, pool_w1, score,
                                              N0, N0, NTOT / 8);
    k_topk_map<<<B, 1024, 0, stream>>>(score, sidxA, mapc, N0, K1, 1);
    k_rpart<<<dim3(RSEG, B), 256, 0, stream>>>(abuf, sidxA, score, pm1, ps1, N0, K1);
    k_proj30p<<<B * K1 / 64, 256, 0, stream>>>(abuf, sidxA, score, Wc2, b_rel2,
                                               rtbuf, N0, K1);

    // ---- layer 2 (no sort: reuse layer-1 runs via sidxA + mapc filter) ----
    k_gather<1><<<B * K1 / 8, 256, 0, stream>>>(sA, runSA, runLA, sidxA, nullptr, mapc,
                                                rtbuf, abuf, pool_w2, score,
                                                K1, K1, B * K1 / 8);
    k_topk_map<<<B, 1024, 0, stream>>>(score, sidxB, mapc, K1, K2, 0);
    k_rpart<<<dim3(RSEG, B), 256, 0, stream>>>(abuf, sidxB, score, pm2, ps2, K1, K2);
    k_proj30p<<<B * K2 / 64, 256, 0, stream>>>(abuf, sidxB, score, Wc3, b_rel3,
                                               rtbuf, K1, K2);

    // ---- layer 3 ----
    k_gather<2><<<B * K2 / 8, 256, 0, stream>>>(sA, runSA, runLA, sidxA, sidxB, mapc,
                                                rtbuf, abuf, pool_w3, score,
                                                K2, K2, B * K2 / 8);
    k_topk_map<<<B, 1024, 0, stream>>>(score, sidxC, mapc, K2, K3, 0);
    k_rpart<<<dim3(RSEG, B), 256, 0, stream>>>(abuf, sidxC, score, pm3, ps3, K2, K3);

    // ---- heads ----
    k_zfin<<<B, 64, 0, stream>>>(pm1, ps1, pm2, ps2, pm3, ps3, zb);
    k_mlp1<<<NH * B, 256, 0, stream>>>(zb, head_W1, head_b1, a1);
    k_mlp2<<<NH * 15, 256, 0, stream>>>(a1, head_W2, head_b2, a2);
    k_mlp3<<<NH * B, 64, 0, stream>>>(a2, head_W3, head_b3, (float*)d_out);
}

// Round 14
// 591.428 us; speedup vs baseline: 1.1790x; 1.0725x over previous
//
#include <hip/hip_runtime.h>
#include <hip/hip_bf16.h>

#define B 64
#define N0 2048
#define DEG 16
#define IN_DIM 128
#define H 30
#define NH 11
#define K1 1844
#define K2 1660
#define K3 1494
#define NTOT (B * N0)        /* 131072 */
#define ETOT (NTOT * DEG)    /* 2097152 */
#define RSTRIDE 32           /* row stride for h */
#define ESTRIDE1 32768       /* layer-1 CSR capacity per graph */
#define RSEG 16              /* readout segments per graph */
/* rt layout: 4 planes [NTOT][16]; plane cg holds combined cols cg*15..cg*15+14
   (cg 0,1 = r cols 0-29; cg 2,3 = t cols 0-29). 16th col = pad -> every
   thread-store is one full aligned 64B line. */

// ---------------------------------------------------------------------------
// Prep: fold layernorm gamma into layer-1 weights; combine rel/root weights.
// ---------------------------------------------------------------------------
__global__ __launch_bounds__(256) void k_prep(
    const float* __restrict__ ln_g, const float* __restrict__ ln_b,
    const float* __restrict__ Wrel1, const float* __restrict__ brel1, const float* __restrict__ Wroot1,
    const float* __restrict__ Wrel2, const float* __restrict__ Wroot2,
    const float* __restrict__ Wrel3, const float* __restrict__ Wroot3,
    float* __restrict__ Wc1, float* __restrict__ S1, float* __restrict__ T1,
    float* __restrict__ Wc2, float* __restrict__ Wc3)
{
    int tid = threadIdx.x;
    for (int i = tid; i < IN_DIM * 60; i += 256) {
        int j = i / 60, c = i - j * 60;
        float w = (c < H) ? Wrel1[j * H + c] : Wroot1[j * H + (c - H)];
        Wc1[i] = w * ln_g[j];
    }
    if (tid < 60) {
        int c = tid;
        float s = 0.f, tt = 0.f;
        for (int j = 0; j < IN_DIM; ++j) {
            float w = (c < H) ? Wrel1[j * H + c] : Wroot1[j * H + (c - H)];
            s += w * ln_g[j];
            tt += w * ln_b[j];
        }
        S1[c] = s;
        T1[c] = (c < H) ? tt : tt + brel1[c - H];
    }
    for (int i = tid; i < H * 60; i += 256) {
        int j = i / 60, c = i - j * 60;
        Wc2[i] = (c < H) ? Wrel2[j * H + c] : Wroot2[j * H + (c - H)];
        Wc3[i] = (c < H) ? Wrel3[j * H + c] : Wroot3[j * H + (c - H)];
    }
}

// ---------------------------------------------------------------------------
// Layer 1 LN+proj (r6 structure -- best of 6 variants at 66-71us): thread =
// row; full W (30KB) staged in LDS, read via broadcast float4; x prefetched
// one jb ahead. Stores: 4 full 64B lines into the 4 rt planes (coalesced
// across lane-consecutive rows).
// ---------------------------------------------------------------------------
__global__ __launch_bounds__(256) void k_lnproj(
    const float* __restrict__ x, const float* __restrict__ Wc,
    const float* __restrict__ S, const float* __restrict__ T,
    float* __restrict__ rt)
{
    __shared__ float wlds[IN_DIM * 60];
    for (int i = threadIdx.x; i < IN_DIM * 60 / 4; i += 256)
        ((float4*)wlds)[i] = ((const float4*)Wc)[i];
    __syncthreads();
    int row = blockIdx.x * 256 + threadIdx.x;
    const float4* xr4 = (const float4*)(x + (size_t)row * IN_DIM);
    float acc[60];
#pragma unroll
    for (int c = 0; c < 60; ++c) acc[c] = 0.f;
    float sum = 0.f, sumsq = 0.f;
    float4 qa = xr4[0], qb = xr4[1];
    for (int jb = 0; jb < 16; ++jb) {
        float xs[8] = {qa.x, qa.y, qa.z, qa.w, qb.x, qb.y, qb.z, qb.w};
        if (jb < 15) { qa = xr4[jb * 2 + 2]; qb = xr4[jb * 2 + 3]; }
#pragma unroll
        for (int u = 0; u < 8; ++u) {
            float xv = xs[u];
            sum += xv; sumsq += xv * xv;
            const float4* w4 = (const float4*)&wlds[(jb * 8 + u) * 60];
#pragma unroll
            for (int c4 = 0; c4 < 15; ++c4) {
                float4 wv = w4[c4];
                acc[c4 * 4 + 0] += xv * wv.x;
                acc[c4 * 4 + 1] += xv * wv.y;
                acc[c4 * 4 + 2] += xv * wv.z;
                acc[c4 * 4 + 3] += xv * wv.w;
            }
        }
    }
    float mean = sum * (1.f / 128.f);
    float var = sumsq * (1.f / 128.f) - mean * mean;
    float rstd = 1.0f / sqrtf(var + 1e-5f);
#pragma unroll
    for (int cg = 0; cg < 4; ++cg) {
        float o[16];
#pragma unroll
        for (int c = 0; c < 15; ++c) {
            int cc = cg * 15 + c;
            o[c] = rstd * (acc[cc] - mean * S[cc]) + T[cc];
        }
        o[15] = 0.f;
        float4* op = (float4*)(rt + ((size_t)cg * NTOT + row) * 16);
        op[0] = make_float4(o[0], o[1], o[2], o[3]);
        op[1] = make_float4(o[4], o[5], o[6], o[7]);
        op[2] = make_float4(o[8], o[9], o[10], o[11]);
        op[3] = make_float4(o[12], o[13], o[14], o[15]);
    }
}

// ---------------------------------------------------------------------------
// Pooled projection (r11 v4 -- best plane-rt variant): thread = (pooled row,
// 15-col group), grid (B*k/256, 4). W wave-uniform global (7KB -> scalar
// cache, unlike lnproj's 30KB); full-line plane stores.
// ---------------------------------------------------------------------------
__global__ __launch_bounds__(256) void k_proj30p(
    const float* __restrict__ hbuf, const int* __restrict__ sidx,
    const float* __restrict__ score, const float* __restrict__ Wc,
    const float* __restrict__ brel, float* __restrict__ rt,
    int n_old, int k)
{
    int cg = blockIdx.y;
    int row = blockIdx.x * 256 + threadIdx.x;  // [0, B*k) exact grid
    int g = row / k, j = row - g * k;
    int idx = sidx[g * k + j];
    float val = score[g * n_old + idx];
    const float* hr = hbuf + (size_t)(g * n_old + idx) * RSTRIDE;
    const float4* hr4 = (const float4*)hr;
    const float* wbase = Wc + cg * 15;
    float acc[15];
#pragma unroll
    for (int c = 0; c < 15; ++c) acc[c] = 0.f;
#pragma unroll
    for (int m4 = 0; m4 < 7; ++m4) {
        float4 hq = hr4[m4];
        float xs[4] = {hq.x, hq.y, hq.z, hq.w};
#pragma unroll
        for (int u = 0; u < 4; ++u) {
            float xv = xs[u];
            const float* wrow = wbase + (m4 * 4 + u) * 60;   // wave-uniform
#pragma unroll
            for (int c = 0; c < 15; ++c) acc[c] += xv * wrow[c];
        }
    }
    {   // tail m = 28, 29
        float2 h2 = *(const float2*)(hr + 28);
        const float* w28 = wbase + 28 * 60;
        const float* w29 = wbase + 29 * 60;
#pragma unroll
        for (int c = 0; c < 15; ++c)
            acc[c] += h2.x * w28[c] + h2.y * w29[c];
    }
    bool isR = (cg < 2);
    float o[16];
#pragma unroll
    for (int c = 0; c < 15; ++c) {
        float bv = isR ? 0.f : brel[(cg - 2) * 15 + c];
        o[c] = val * acc[c] + bv;
    }
    o[15] = 0.f;
    float4* op = (float4*)(rt + ((size_t)cg * NTOT + row) * 16);
    op[0] = make_float4(o[0], o[1], o[2], o[3]);
    op[1] = make_float4(o[4], o[5], o[6], o[7]);
    op[2] = make_float4(o[8], o[9], o[10], o[11]);
    op[3] = make_float4(o[12], o[13], o[14], o[15]);
}

// ---------------------------------------------------------------------------
// Layer-1 counting sort (the only sort in the pipeline).
// ---------------------------------------------------------------------------
__global__ __launch_bounds__(1024) void k_hist1(
    const int* __restrict__ dst, unsigned short* __restrict__ rank,
    int* __restrict__ chunkCnt)
{
    __shared__ unsigned int cnt[2048];
    int chunk = blockIdx.x, g = chunk >> 2;
    for (int i = threadIdx.x; i < 2048; i += 1024) cnt[i] = 0;
    __syncthreads();
    int e0 = chunk * 8192;
#pragma unroll
    for (int u = 0; u < 8; ++u) {
        int e = e0 + u * 1024 + threadIdx.x;
        int d = dst[e] - g * N0;
        rank[e] = (unsigned short)atomicAdd(&cnt[d], 1u);
    }
    __syncthreads();
    for (int i = threadIdx.x; i < 2048; i += 1024) chunkCnt[chunk * 2048 + i] = cnt[i];
}

__global__ __launch_bounds__(1024) void k_scan(
    int* __restrict__ chunkCnt, int* __restrict__ runStart, int* __restrict__ runLen)
{
    __shared__ int bufA[2048], bufB[2048];
    int g = blockIdx.x;
    int c0[2], c1[2], c2[2], tt[2];
    for (int h2 = 0; h2 < 2; ++h2) {
        int d = threadIdx.x + h2 * 1024;
        c0[h2] = chunkCnt[(g * 4 + 0) * 2048 + d];
        c1[h2] = chunkCnt[(g * 4 + 1) * 2048 + d];
        c2[h2] = chunkCnt[(g * 4 + 2) * 2048 + d];
        int c3 = chunkCnt[(g * 4 + 3) * 2048 + d];
        tt[h2] = c0[h2] + c1[h2] + c2[h2] + c3;
        bufA[d] = tt[h2];
    }
    __syncthreads();
    int* s_ = bufA; int* d_ = bufB;
    for (int off = 1; off < 2048; off <<= 1) {
        for (int h2 = 0; h2 < 2; ++h2) {
            int d = threadIdx.x + h2 * 1024;
            int v = s_[d];
            if (d >= off) v += s_[d - off];
            d_[d] = v;
        }
        __syncthreads();
        int* tmp = s_; s_ = d_; d_ = tmp;
    }
    for (int h2 = 0; h2 < 2; ++h2) {
        int d = threadIdx.x + h2 * 1024;
        int ex = s_[d] - tt[h2];
        runStart[g * 2048 + d] = ex;
        runLen[g * 2048 + d] = tt[h2];
        chunkCnt[(g * 4 + 0) * 2048 + d] = ex;
        chunkCnt[(g * 4 + 1) * 2048 + d] = ex + c0[h2];
        chunkCnt[(g * 4 + 2) * 2048 + d] = ex + c0[h2] + c1[h2];
        chunkCnt[(g * 4 + 3) * 2048 + d] = ex + c0[h2] + c1[h2] + c2[h2];
    }
}

__global__ __launch_bounds__(1024) void k_scat1(
    const int* __restrict__ src, const int* __restrict__ dst, const float* __restrict__ ew,
    const unsigned short* __restrict__ rank, const int* __restrict__ chunkOff,
    float2* __restrict__ sOut)
{
    int chunk = blockIdx.x, g = chunk >> 2;
    int e0 = chunk * 8192;
#pragma unroll
    for (int u = 0; u < 8; ++u) {
        int e = e0 + u * 1024 + threadIdx.x;
        int d = dst[e] - g * N0;
        int pos = chunkOff[chunk * 2048 + d] + (int)rank[e];
        sOut[(size_t)g * ESTRIDE1 + pos] = make_float2(__int_as_float(src[e]), ew[e]);
    }
}

// ---------------------------------------------------------------------------
// Run-major aggregation over the LAYER-1 CSR for ALL layers. Reads rt planes:
// r lane j -> plane (j<15?0:1) offset j%15; t -> plane 2/3. Zero atomics;
// fused +t/relu and score.
// ---------------------------------------------------------------------------
template<int LVL>
__global__ __launch_bounds__(256) void k_gather(
    const float2* __restrict__ sE, const int* __restrict__ runS, const int* __restrict__ runL,
    const int* __restrict__ ind1, const int* __restrict__ ind2, const int* __restrict__ mapc,
    const float* __restrict__ rt, float* __restrict__ h,
    const float* __restrict__ poolw, float* __restrict__ score,
    int n, int rK, int nblocks)
{
    int b = blockIdx.x;
    int cpx = nblocks >> 3;                 // XCD-chunked swizzle
    b = (b & 7) * cpx + (b >> 3);
    int slot = threadIdx.x >> 5, j = threadIdx.x & 31;
    int v = b * 8 + slot;
    int g = v / n;
    int local = v - g * n;
    int v1 = local;
    if (LVL >= 2) v1 = ind2[g * K2 + v1];
    if (LVL >= 1) v1 = ind1[g * K1 + v1];
    int s0 = runS[g * 2048 + v1], len = runL[g * 2048 + v1];
    const float2* meta = sE + (size_t)g * ESTRIDE1 + s0;
    int rbase = g * rK;
    int oj = (j < 15) ? j : ((j < 30) ? j - 15 : 14);
    const float* rplane = rt + ((j < 15) ? 0 : ((size_t)NTOT * 16)) + oj;
    float acc = 0.f;
    for (int c = 0; c < len; c += 8) {
        int lim = len - c; if (lim > 8) lim = 8;
        float2 m[8];
#pragma unroll
        for (int u = 0; u < 8; ++u) m[u] = meta[c + (u < lim ? u : 0)];
        int rowv[8]; float wv[8];
#pragma unroll
        for (int u = 0; u < 8; ++u) {
            int srcg = __float_as_int(m[u].x);
            float w = (u < lim) ? m[u].y : 0.f;
            if (LVL == 0) {
                rowv[u] = srcg;
            } else {
                int ss = mapc[srcg];
                rowv[u] = rbase + (ss < 0 ? 0 : ss);
                w = (ss < 0) ? 0.f : w;
            }
            wv[u] = w;
        }
#pragma unroll
        for (int u = 0; u < 8; ++u)
            acc += rplane[(size_t)rowv[u] * 16] * wv[u];
    }
    float wj = (j < H) ? poolw[j] : 0.f;
    float hval = 0.f;
    if (j < H) {
        size_t tp = (j < 15) ? 2 : 3;
        hval = fmaxf(acc + rt[(tp * NTOT + v) * 16 + oj], 0.f);
        h[(size_t)v * RSTRIDE + j] = hval;
    }
    float p = hval * wj, q = wj * wj;
#pragma unroll
    for (int off = 16; off > 0; off >>= 1) {
        p += __shfl_xor(p, off, 32);
        q += __shfl_xor(q, off, 32);
    }
    if (j == 0) score[v] = tanhf(p / sqrtf(q));
}

// ---------------------------------------------------------------------------
// Top-k (desc score, asc idx; jax.lax.top_k tie-break) + cumulative map.
// ---------------------------------------------------------------------------
__global__ __launch_bounds__(1024) void k_topk_map(
    const float* __restrict__ score, int* __restrict__ sidx, int* __restrict__ mapc,
    int n, int k, int first)
{
    __shared__ unsigned long long keys[2048];
    __shared__ int inv[2048];
    int g = blockIdx.x;
    for (int i = threadIdx.x; i < 2048; i += 1024) {
        unsigned long long key = ~0ull;
        if (i < n) {
            float s = score[g * n + i];
            if (s == 0.f) s = 0.f;                 // canonicalize -0 -> +0
            unsigned u = __float_as_uint(s);
            unsigned asc = (u & 0x80000000u) ? ~u : (u | 0x80000000u);
            unsigned desc = ~asc;
            key = ((unsigned long long)desc << 32) | (unsigned)i;
        }
        keys[i] = key;
        inv[i] = -1;
    }
    __syncthreads();
    for (int kk = 2; kk <= 2048; kk <<= 1) {
        for (int jj = kk >> 1; jj > 0; jj >>= 1) {
            for (int i = threadIdx.x; i < 2048; i += 1024) {
                int ixj = i ^ jj;
                if (ixj > i) {
                    unsigned long long a = keys[i], bb = keys[ixj];
                    bool up = ((i & kk) == 0);
                    if ((a > bb) == up) { keys[i] = bb; keys[ixj] = a; }
                }
            }
            __syncthreads();
        }
    }
    for (int j = threadIdx.x; j < k; j += 1024) {
        int idx = (int)(keys[j] & 0xffffffffu);
        sidx[g * k + j] = idx;
        inv[idx] = j;
    }
    __syncthreads();
    if (first) {
        for (int v = threadIdx.x; v < N0; v += 1024)
            mapc[g * N0 + v] = inv[v];
    } else {
        for (int v = threadIdx.x; v < N0; v += 1024) {
            int m = mapc[g * N0 + v];
            mapc[g * N0 + v] = (m >= 0) ? inv[m] : -1;
        }
    }
}

// ---------------------------------------------------------------------------
// Segmented readout: grid (RSEG, B). Partial [max;sum] over a row slice.
// ---------------------------------------------------------------------------
__global__ __launch_bounds__(256) void k_rpart(
    const float* __restrict__ hbuf, const int* __restrict__ sidx,
    const float* __restrict__ score, float* __restrict__ pmax, float* __restrict__ psum,
    int n_old, int k)
{
    __shared__ float smax[8][32], ssum[8][32];
    int g = blockIdx.y, seg = blockIdx.x;
    int clen = (k + RSEG - 1) / RSEG;
    int start = seg * clen;
    int end = start + clen; if (end > k) end = k;
    int f = threadIdx.x & 31, rr = threadIdx.x >> 5;
    float mx = -INFINITY, sm = 0.f;
    if (f < H) {
        for (int j = start + rr; j < end; j += 8) {
            int idx = sidx[g * k + j];
            float val = score[g * n_old + idx];
            float v = hbuf[(size_t)(g * n_old + idx) * RSTRIDE + f] * val;
            mx = fmaxf(mx, v);
            sm += v;
        }
    }
    smax[rr][f] = mx; ssum[rr][f] = sm;
    __syncthreads();
    if (rr == 0) {
        for (int q = 1; q < 8; ++q) { mx = fmaxf(mx, smax[q][f]); sm += ssum[q][f]; }
        pmax[(g * RSEG + seg) * 32 + f] = mx;
        psum[(g * RSEG + seg) * 32 + f] = sm;
    }
}

// Finalize all 3 readouts + z = relu(x1+x2+x3). grid B, block 64.
__global__ __launch_bounds__(64) void k_zfin(
    const float* __restrict__ pm1, const float* __restrict__ ps1,
    const float* __restrict__ pm2, const float* __restrict__ ps2,
    const float* __restrict__ pm3, const float* __restrict__ ps3,
    float* __restrict__ z)
{
    int g = blockIdx.x, c = threadIdx.x;
    if (c >= 60) return;
    float v1, v2, v3;
    if (c < H) {
        float m1 = -INFINITY, m2 = -INFINITY, m3 = -INFINITY;
        for (int s = 0; s < RSEG; ++s) {
            m1 = fmaxf(m1, pm1[(g * RSEG + s) * 32 + c]);
            m2 = fmaxf(m2, pm2[(g * RSEG + s) * 32 + c]);
            m3 = fmaxf(m3, pm3[(g * RSEG + s) * 32 + c]);
        }
        v1 = m1; v2 = m2; v3 = m3;
    } else {
        int f = c - H;
        float s1 = 0.f, s2 = 0.f, s3 = 0.f;
        for (int s = 0; s < RSEG; ++s) {
            s1 += ps1[(g * RSEG + s) * 32 + f];
            s2 += ps2[(g * RSEG + s) * 32 + f];
            s3 += ps3[(g * RSEG + s) * 32 + f];
        }
        v1 = s1 / (float)K1; v2 = s2 / (float)K2; v3 = s3 / (float)K3;
    }
    z[g * 60 + c] = fmaxf(v1 + v2 + v3, 0.f);
}

// a1[h,b,o] = relu(sum_d z[b,d]*W1[h,d,o] + b1[h,o]),  o<240, d<60
__global__ __launch_bounds__(256) void k_mlp1(
    const float* __restrict__ z, const float* __restrict__ W,
    const float* __restrict__ bias, float* __restrict__ a)
{
    int hb = blockIdx.x, hh = hb >> 6, b = hb & 63;
    __shared__ float zr[60];
    if (threadIdx.x < 60) zr[threadIdx.x] = z[b * 60 + threadIdx.x];
    __syncthreads();
    int o = threadIdx.x;
    if (o < 240) {
        float acc = bias[hh * 240 + o];
        const float* Wp = W + hh * 60 * 240;
#pragma unroll
        for (int d = 0; d < 60; ++d) acc += zr[d] * Wp[d * 240 + o];
        a[(hh * B + b) * 240 + o] = fmaxf(acc, 0.f);
    }
}

// a2 GEMM: grid (11 heads x 15 col-tiles of 64); a1 tile in LDS.
__global__ __launch_bounds__(256) void k_mlp2(
    const float* __restrict__ a1, const float* __restrict__ W,
    const float* __restrict__ bias, float* __restrict__ a2)
{
    __shared__ float a1t[64 * 240];
    int hh = blockIdx.x / 15, ct = blockIdx.x % 15;
    const float4* ag = (const float4*)(a1 + (size_t)hh * B * 240);
    for (int i = threadIdx.x; i < 64 * 240 / 4; i += 256)
        ((float4*)a1t)[i] = ag[i];
    __syncthreads();
    int col = threadIdx.x & 63, rg = threadIdx.x >> 6;
    const float* Wp = W + (size_t)hh * 240 * 960 + ct * 64 + col;
    float acc[16];
#pragma unroll
    for (int i = 0; i < 16; ++i) acc[i] = 0.f;
#pragma unroll 4
    for (int o = 0; o < 240; ++o) {
        float w = Wp[(size_t)o * 960];
        const float* ar = &a1t[0];
#pragma unroll
        for (int i = 0; i < 16; ++i)
            acc[i] += w * ar[(rg * 16 + i) * 240 + o];
    }
    float bv = bias[hh * 960 + ct * 64 + col];
#pragma unroll
    for (int i = 0; i < 16; ++i)
        a2[((size_t)hh * B + rg * 16 + i) * 960 + ct * 64 + col] =
            fmaxf(acc[i] + bv, 0.f);
}

// out[h,b,q] = sum_p a2[h,b,p]*W3[h,p,q] + b3[h,q],  q<8, p<960
__global__ __launch_bounds__(64) void k_mlp3(
    const float* __restrict__ a2, const float* __restrict__ W,
    const float* __restrict__ bias, float* __restrict__ out)
{
    int hb = blockIdx.x, hh = hb >> 6, b = hb & 63;
    __shared__ float ar[960];
    __shared__ float part[64];
    for (int i = threadIdx.x; i < 960; i += 64) ar[i] = a2[(hh * B + b) * 960 + i];
    __syncthreads();
    int q = threadIdx.x & 7, c = threadIdx.x >> 3;
    const float* Wp = W + hh * 960 * 8;
    float acc = 0.f;
    for (int p = c; p < 960; p += 8) acc += ar[p] * Wp[p * 8 + q];
    part[threadIdx.x] = acc;
    __syncthreads();
    if (threadIdx.x < 8) {
        float s = bias[hh * 8 + threadIdx.x];
        for (int cc = 0; cc < 8; ++cc) s += part[cc * 8 + threadIdx.x];
        out[(hh * B + b) * 8 + threadIdx.x] = s;
    }
}

// ---------------------------------------------------------------------------
extern "C" void kernel_launch(void* const* d_in, const int* in_sizes, int n_in,
                              void* d_out, int out_size, void* d_ws, size_t ws_size,
                              hipStream_t stream)
{
    const float* x       = (const float*)d_in[0];
    const int*   eidx    = (const int*)d_in[1];
    const int*   src0    = eidx;
    const int*   dst0    = eidx + ETOT;
    const float* ew0     = (const float*)d_in[2];
    const float* ln_g    = (const float*)d_in[4];
    const float* ln_b    = (const float*)d_in[5];
    const float* W_rel1  = (const float*)d_in[6];
    const float* b_rel1  = (const float*)d_in[7];
    const float* W_root1 = (const float*)d_in[8];
    const float* W_rel2  = (const float*)d_in[9];
    const float* b_rel2  = (const float*)d_in[10];
    const float* W_root2 = (const float*)d_in[11];
    const float* W_rel3  = (const float*)d_in[12];
    const float* b_rel3  = (const float*)d_in[13];
    const float* W_root3 = (const float*)d_in[14];
    const float* pool_w1 = (const float*)d_in[15];
    const float* pool_w2 = (const float*)d_in[16];
    const float* pool_w3 = (const float*)d_in[17];
    const float* head_W1 = (const float*)d_in[18];
    const float* head_b1 = (const float*)d_in[19];
    const float* head_W2 = (const float*)d_in[20];
    const float* head_b2 = (const float*)d_in[21];
    const float* head_W3 = (const float*)d_in[22];
    const float* head_b3 = (const float*)d_in[23];

    // ---- workspace carve (~72 MB) ----
    float* ws     = (float*)d_ws;
    float* rtbuf  = ws;                               // 4 planes x NTOT x 16
    float* abuf   = rtbuf + (size_t)NTOT * 64;        // NTOT*32 (h)
    float2* sA    = (float2*)(abuf + (size_t)NTOT * RSTRIDE); // B*ESTRIDE1
    float* score  = (float*)(sA + (size_t)B * ESTRIDE1);      // NTOT
    int*   sidxA  = (int*)(score + NTOT);             // B*K1
    int*   sidxB  = sidxA + B * K1;                   // B*K2
    int*   sidxC  = sidxB + B * K2;                   // B*K3
    int*   mapc   = sidxC + B * K3;                   // NTOT
    int*   runSA  = mapc + NTOT;                      // B*2048
    int*   runLA  = runSA + B * 2048;                 // B*2048
    float* pm1    = (float*)(runLA + B * 2048);       // B*RSEG*32 each
    float* ps1    = pm1 + B * RSEG * 32;
    float* pm2    = ps1 + B * RSEG * 32;
    float* ps2    = pm2 + B * RSEG * 32;
    float* pm3    = ps2 + B * RSEG * 32;
    float* ps3    = pm3 + B * RSEG * 32;
    float* zb     = ps3 + B * RSEG * 32;              // B*60
    float* Wc1    = zb + B * 60;                      // 128*60
    float* S1     = Wc1 + IN_DIM * 60;
    float* T1     = S1 + 60;
    float* Wc2    = T1 + 60;                          // 30*60
    float* Wc3    = Wc2 + H * 60;
    // aliases into abuf (dead before gather<0>): chunk counters + edge ranks
    int* chunkBuf         = (int*)abuf;                                  // 256*2048 ints
    unsigned short* rank  = (unsigned short*)((char*)abuf + (4u << 20)); // ETOT u16
    // heads alias rtbuf (dead after layer-3 gather)
    float* a1 = rtbuf;
    float* a2 = a1 + NH * B * 240;

    k_prep<<<1, 256, 0, stream>>>(ln_g, ln_b, W_rel1, b_rel1, W_root1,
                                  W_rel2, W_root2, W_rel3, W_root3,
                                  Wc1, S1, T1, Wc2, Wc3);

    // ---- layer-1 CSR (the only sort) ----
    k_hist1<<<256, 1024, 0, stream>>>(dst0, rank, chunkBuf);
    k_scan<<<B, 1024, 0, stream>>>(chunkBuf, runSA, runLA);
    k_scat1<<<256, 1024, 0, stream>>>(src0, dst0, ew0, rank, chunkBuf, sA);

    // ---- layer 1 ----
    k_lnproj<<<NTOT / 256, 256, 0, stream>>>(x, Wc1, S1, T1, rtbuf);
    k_gather<0><<<NTOT / 8, 256, 0, stream>>>(sA, runSA, runLA, nullptr, nullptr, nullptr,
                                              rtbuf, abuf, pool_w1, score,
                                              N0, N0, NTOT / 8);
    k_topk_map<<<B, 1024, 0, stream>>>(score, sidxA, mapc, N0, K1, 1);
    k_rpart<<<dim3(RSEG, B), 256, 0, stream>>>(abuf, sidxA, score, pm1, ps1, N0, K1);
    k_proj30p<<<dim3(B * K1 / 256, 4), 256, 0, stream>>>(abuf, sidxA, score, Wc2, b_rel2,
                                                         rtbuf, N0, K1);

    // ---- layer 2 (no sort: reuse layer-1 runs via sidxA + mapc filter) ----
    k_gather<1><<<B * K1 / 8, 256, 0, stream>>>(sA, runSA, runLA, sidxA, nullptr, mapc,
                                                rtbuf, abuf, pool_w2, score,
                                                K1, K1, B * K1 / 8);
    k_topk_map<<<B, 1024, 0, stream>>>(score, sidxB, mapc, K1, K2, 0);
    k_rpart<<<dim3(RSEG, B), 256, 0, stream>>>(abuf, sidxB, score, pm2, ps2, K1, K2);
    k_proj30p<<<dim3(B * K2 / 256, 4), 256, 0, stream>>>(abuf, sidxB, score, Wc3, b_rel3,
                                                         rtbuf, K1, K2);

    // ---- layer 3 ----
    k_gather<2><<<B * K2 / 8, 256, 0, stream>>>(sA, runSA, runLA, sidxA, sidxB, mapc,
                                                rtbuf, abuf, pool_w3, score,
                                                K2, K2, B * K2 / 8);
    k_topk_map<<<B, 1024, 0, stream>>>(score, sidxC, mapc, K2, K3, 0);
    k_rpart<<<dim3(RSEG, B), 256, 0, stream>>>(abuf, sidxC, score, pm3, ps3, K2, K3);

    // ---- heads ----
    k_zfin<<<B, 64, 0, stream>>>(pm1, ps1, pm2, ps2, pm3, ps3, zb);
    k_mlp1<<<NH * B, 256, 0, stream>>>(zb, head_W1, head_b1, a1);
    k_mlp2<<<NH * 15, 256, 0, stream>>>(a1, head_W2, head_b2, a2);
    k_mlp3<<<NH * B, 64, 0, stream>>>(a2, head_W3, head_b3, (float*)d_out);
}